// Round 2
// baseline (173.054 us; speedup 1.0000x reference)
//
#include <hip/hip_runtime.h>
#include <hip/hip_bf16.h>
#include <stdint.h>

#define R_ 256
#define S_ 128
#define C_ 256
#define CO_ 32
#define OUT_ 128
#define LN_EPS 1e-5f
#define EPS_ 1e-3f

typedef __attribute__((ext_vector_type(8))) short bf16x8;
typedef __attribute__((ext_vector_type(4))) float f32x4;

static __device__ __forceinline__ unsigned short f2bf(float f) {
  union { float f; uint32_t u; } cv; cv.f = f;
  uint32_t u = cv.u;
  uint32_t r = (u + 0x7FFFu + ((u >> 16) & 1u)) >> 16;
  return (unsigned short)r;
}

// ---------------- weight prep: wcat[co][c] = bf16(gamma[c]*w[co][c]),
// g1[co] = sum_c gamma*w, g0[co] = sum_c beta*w, bcat = b_left||b_right ----
__global__ void k_prep_w(const float* wl, const float* wr, const float* gamma,
                         const float* beta, const float* bl, const float* br,
                         unsigned short* wcat, float* g1, float* g0, float* bcat) {
  int co = blockIdx.x;   // 0..63
  int c = threadIdx.x;   // 0..255
  const float* src = (co < 32) ? (wl + co * C_) : (wr + (co - 32) * C_);
  float w = src[c], g = gamma[c], bt = beta[c];
  float wg = w * g;
  wcat[co * C_ + c] = f2bf(wg);
  __shared__ float red1[256], red0[256];
  red1[c] = wg; red0[c] = w * bt;
  __syncthreads();
  for (int off = 128; off > 0; off >>= 1) {
    if (c < off) { red1[c] += red1[c + off]; red0[c] += red0[c + off]; }
    __syncthreads();
  }
  if (c == 0) {
    g1[co] = red1[0];
    g0[co] = red0[0];
    bcat[co] = (co < 32) ? bl[co] : br[co - 32];
  }
}

// ---------------- cast w_o to bf16 ----------------
__global__ void k_cast_wo(const float* wo, unsigned short* wob) {
  int t = blockIdx.x * 256 + threadIdx.x;   // 0..32767, 4 elems each
  float4 v = ((const float4*)wo)[t];
  ushort4 o;
  o.x = f2bf(v.x); o.y = f2bf(v.y); o.z = f2bf(v.z); o.w = f2bf(v.w);
  ((ushort4*)wob)[t] = o;
}

// ---------------- inv norm table: 1/(eps + sum_s mask[s,i]*mask[s,j]) ------
__global__ void k_norm(const float* mask, float* invn) {
  int i = blockIdx.x, j = threadIdx.x;
  float a = 0.f;
  for (int s = 0; s < S_; ++s) a += mask[s * R_ + i] * mask[s * R_ + j];
  invn[i * R_ + j] = 1.0f / (EPS_ + a);
}

// ---------------- projection kernel: one block per r ----------------
// computes left[r][co][s], right[r][co][s] (bf16, k-major) with LN folded in
#define AP 264   // padded u16 per LDS row (256 + 8) -> 528B stride
__global__ __launch_bounds__(256) void k_proj(
    const float* act, const float* mask, const unsigned short* wcat,
    const float* g1v, const float* g0v, const float* bcv,
    unsigned short* leftg, unsigned short* rightg) {
  __shared__ unsigned short a_bf[S_ * AP];   // 67584 B
  __shared__ unsigned short w_l[64 * AP];    // 33792 B (reused as trans)
  __shared__ float mu_s[S_], rs_s[S_], mk_s[S_];
  __shared__ float g1s[64], g0s[64], bcs[64];
  int tid = threadIdx.x;
  int r = blockIdx.x;

  // pass 1: act[r] (128x256 f32) -> bf16 LDS, coalesced flat
  const float4* actv = (const float4*)(act + (size_t)r * (S_ * C_));
  for (int it = 0; it < 32; ++it) {
    int f = tid + it * 256;          // float4 index 0..8191
    int s = f >> 6;
    int c4 = (f & 63) * 4;
    float4 v = actv[f];
    ushort4 o;
    o.x = f2bf(v.x); o.y = f2bf(v.y); o.z = f2bf(v.z); o.w = f2bf(v.w);
    *(ushort4*)&a_bf[s * AP + c4] = o;
  }
  // stage wcat (64x256 u16)
  const uint4* wsrc = (const uint4*)wcat;
  for (int it = 0; it < 8; ++it) {
    int f = tid + it * 256;          // 0..2047 chunks of 8 u16
    int co = f >> 5, ch = f & 31;
    *(uint4*)&w_l[co * AP + ch * 8] = wsrc[f];
  }
  if (tid < 128) mk_s[tid] = mask[tid * R_ + r];
  if (tid < 64) { g1s[tid] = g1v[tid]; g0s[tid] = g0v[tid]; bcs[tid] = bcv[tid]; }
  __syncthreads();

  // row stats from the bf16'd rows
  if (tid < 128) {
    float sum = 0.f, sq = 0.f;
    for (int i = 0; i < 32; ++i) {
      uint4 v = *(const uint4*)&a_bf[tid * AP + i * 8];
      uint32_t ws_[4] = {v.x, v.y, v.z, v.w};
#pragma unroll
      for (int q = 0; q < 4; ++q) {
        union { uint32_t u; float f; } lo, hi;
        lo.u = ws_[q] << 16;
        hi.u = ws_[q] & 0xFFFF0000u;
        sum += lo.f + hi.f;
        sq += lo.f * lo.f + hi.f * hi.f;
      }
    }
    float mu = sum * (1.0f / C_);
    float var = sq * (1.0f / C_) - mu * mu;
    mu_s[tid] = mu;
    rs_s[tid] = rsqrtf(var + LN_EPS);
  }
  __syncthreads();

  // GEMM: M=128(s) x N=64(co) x K=256, 4 waves each own 32 rows
  int lane = tid & 63, wid = tid >> 6;
  int l15 = lane & 15, l4 = lane >> 4;
  f32x4 acc[2][4];
#pragma unroll
  for (int a = 0; a < 2; ++a)
#pragma unroll
    for (int b = 0; b < 4; ++b) acc[a][b] = (f32x4){0.f, 0.f, 0.f, 0.f};
  for (int ks = 0; ks < 8; ++ks) {
    bf16x8 af[2], bfr[4];
#pragma unroll
    for (int mf = 0; mf < 2; ++mf) {
      int row = wid * 32 + mf * 16 + l15;
      af[mf] = *(const bf16x8*)&a_bf[row * AP + ks * 32 + l4 * 8];
    }
#pragma unroll
    for (int nf = 0; nf < 4; ++nf) {
      int row = nf * 16 + l15;
      bfr[nf] = *(const bf16x8*)&w_l[row * AP + ks * 32 + l4 * 8];
    }
#pragma unroll
    for (int mf = 0; mf < 2; ++mf)
#pragma unroll
      for (int nf = 0; nf < 4; ++nf)
        acc[mf][nf] = __builtin_amdgcn_mfma_f32_16x16x32_bf16(af[mf], bfr[nf], acc[mf][nf], 0, 0, 0);
  }
  __syncthreads();   // done reading w_l; reuse as transpose buffer

  unsigned short* trans = w_l;   // [64][136] u16, 272B rows
#pragma unroll
  for (int mf = 0; mf < 2; ++mf) {
#pragma unroll
    for (int nf = 0; nf < 4; ++nf) {
      int co = nf * 16 + l15;
      float G1 = g1s[co], G0 = g0s[co], BC = bcs[co];
#pragma unroll
      for (int reg = 0; reg < 4; ++reg) {
        int s = wid * 32 + mf * 16 + l4 * 4 + reg;
        float v = rs_s[s] * acc[mf][nf][reg] - mu_s[s] * rs_s[s] * G1 + G0 + BC;
        v *= mk_s[s];
        trans[co * 136 + s] = f2bf(v);
      }
    }
  }
  __syncthreads();

  // write out [r][co][s], 16B chunks, coalesced
  uint4* lg = (uint4*)leftg;
  uint4* rg = (uint4*)rightg;
  for (int it = 0; it < 4; ++it) {
    int idx = tid + it * 256;      // 0..1023
    int row = idx >> 4, ch = idx & 15;
    uint4 val = *(const uint4*)&trans[row * 136 + ch * 8];
    if (row < 32) lg[((size_t)r * 32 + row) * 16 + ch] = val;
    else          rg[((size_t)r * 32 + (row - 32)) * 16 + ch] = val;
  }
}

// ---------------- main kernel: 8x8 r-tile per block ----------------
#define SROW 136    // u16 per slab row (128 + 8 pad) -> 272B
#define OPROW 1032  // u16 per op row (1024 + 8 pad)  -> 2064B
__global__ __launch_bounds__(512, 2) void k_main(
    const unsigned short* __restrict__ leftg, const unsigned short* __restrict__ rightg,
    const unsigned short* __restrict__ wob, const float* __restrict__ bo,
    const float* __restrict__ invn, float* __restrict__ out) {
  __shared__ __align__(16) unsigned char sm[2 * 256 * 272];   // 139264 B
  unsigned short* sa = (unsigned short*)sm;                    // [256][136]
  unsigned short* sb = (unsigned short*)(sm + 256 * 272);
  unsigned short* opb = (unsigned short*)sm;                   // [64][1032], aliases slabs
  int tid = threadIdx.x;
  int bi = blockIdx.x >> 5, bj = blockIdx.x & 31;

  // stage slabs: 256 rows x 128 u16 each, contiguous in global
  const uint4* lsrc = (const uint4*)leftg + (size_t)bi * 256 * 16;
  const uint4* rsrc = (const uint4*)rightg + (size_t)bj * 256 * 16;
  for (int it = 0; it < 8; ++it) {
    int idx = tid + it * 512;      // 0..4095
    int row = idx >> 4, ch = idx & 15;
    *(uint4*)&sa[row * SROW + ch * 8] = lsrc[idx];
    *(uint4*)&sb[row * SROW + ch * 8] = rsrc[idx];
  }
  __syncthreads();

  int lane = tid & 63, w = tid >> 6;
  int l15 = lane & 15, l4 = lane >> 4;

  // ---- stage A: op[m=(i,c)][n=(j,d)] = sum_s L*R, M=N=256, K=128 ----
  int wm = w >> 2, wn = w & 3;     // 2 m-halves x 4 n-quarters
  f32x4 acc[8][4];
#pragma unroll
  for (int a = 0; a < 8; ++a)
#pragma unroll
    for (int b = 0; b < 4; ++b) acc[a][b] = (f32x4){0.f, 0.f, 0.f, 0.f};
  for (int ks = 0; ks < 4; ++ks) {
    bf16x8 af[8], bfr[4];
#pragma unroll
    for (int mf = 0; mf < 8; ++mf)
      af[mf] = *(const bf16x8*)&sa[(wm * 128 + mf * 16 + l15) * SROW + ks * 32 + l4 * 8];
#pragma unroll
    for (int nf = 0; nf < 4; ++nf)
      bfr[nf] = *(const bf16x8*)&sb[(wn * 64 + nf * 16 + l15) * SROW + ks * 32 + l4 * 8];
#pragma unroll
    for (int mf = 0; mf < 8; ++mf)
#pragma unroll
      for (int nf = 0; nf < 4; ++nf)
        acc[mf][nf] = __builtin_amdgcn_mfma_f32_16x16x32_bf16(af[mf], bfr[nf], acc[mf][nf], 0, 0, 0);
  }
  __syncthreads();   // all slab reads done; opb aliases sa/sb

  // write op as bf16 into [p=(i*8+j)][kk=(c*32+d)]
#pragma unroll
  for (int mf = 0; mf < 8; ++mf) {
    int mbase = wm * 128 + mf * 16 + l4 * 4;
#pragma unroll
    for (int nf = 0; nf < 4; ++nf) {
      int n = wn * 64 + nf * 16 + l15;
      int j = n >> 5, d = n & 31;
#pragma unroll
      for (int reg = 0; reg < 4; ++reg) {
        int m = mbase + reg;
        int i = m >> 5, c = m & 31;
        opb[(i * 8 + j) * OPROW + c * 32 + d] = f2bf(acc[mf][nf][reg]);
      }
    }
  }
  __syncthreads();

  // ---- stage B: out[p][o] = sum_kk op[p][kk]*wo[o][kk], M=64 N=128 K=1024 ----
  int o = w * 16 + l15;            // each wave owns 16 o-columns
  f32x4 acc2[4];
#pragma unroll
  for (int a = 0; a < 4; ++a) acc2[a] = (f32x4){0.f, 0.f, 0.f, 0.f};
  const uint4* wrow = (const uint4*)(wob + (size_t)o * 1024);  // 128 uint4
  uint4 bnext = wrow[l4];          // ks2 = 0
  for (int ks2 = 0; ks2 < 32; ++ks2) {
    uint4 bcur = bnext;
    if (ks2 < 31) bnext = wrow[(ks2 + 1) * 4 + l4];
    bf16x8 b2 = *(const bf16x8*)&bcur;
    bf16x8 a2[4];
#pragma unroll
    for (int mf = 0; mf < 4; ++mf)
      a2[mf] = *(const bf16x8*)&opb[(mf * 16 + l15) * OPROW + ks2 * 32 + l4 * 8];
#pragma unroll
    for (int mf = 0; mf < 4; ++mf)
      acc2[mf] = __builtin_amdgcn_mfma_f32_16x16x32_bf16(a2[mf], b2, acc2[mf], 0, 0, 0);
  }

  float bov = bo[o];
#pragma unroll
  for (int mf = 0; mf < 4; ++mf) {
#pragma unroll
    for (int reg = 0; reg < 4; ++reg) {
      int p = mf * 16 + l4 * 4 + reg;
      int gi = bi * 8 + (p >> 3), gj = bj * 8 + (p & 7);
      float v = (acc2[mf][reg] + bov) * invn[gi * R_ + gj];
      out[((size_t)(gi * R_ + gj)) * OUT_ + o] = v;
    }
  }
}

extern "C" void kernel_launch(void* const* d_in, const int* in_sizes, int n_in,
                              void* d_out, int out_size, void* d_ws, size_t ws_size,
                              hipStream_t stream) {
  (void)in_sizes; (void)n_in; (void)out_size; (void)ws_size;
  const float* act   = (const float*)d_in[0];
  const float* mask  = (const float*)d_in[1];
  const float* gamma = (const float*)d_in[2];
  const float* beta  = (const float*)d_in[3];
  const float* wl    = (const float*)d_in[4];
  const float* bl    = (const float*)d_in[5];
  const float* wr    = (const float*)d_in[6];
  const float* br    = (const float*)d_in[7];
  const float* wo    = (const float*)d_in[8];
  const float* bo    = (const float*)d_in[9];
  float* out = (float*)d_out;
  unsigned char* ws = (unsigned char*)d_ws;
  unsigned short* leftg  = (unsigned short*)(ws + 0);
  unsigned short* rightg = (unsigned short*)(ws + 2097152);
  unsigned short* wob    = (unsigned short*)(ws + 4194304);
  float* invn            = (float*)(ws + 4456448);
  unsigned short* wcat   = (unsigned short*)(ws + 4718592);
  float* g1              = (float*)(ws + 4751360);
  float* g0              = (float*)(ws + 4751616);
  float* bcat            = (float*)(ws + 4751872);

  hipLaunchKernelGGL(k_prep_w, dim3(64), dim3(256), 0, stream,
                     wl, wr, gamma, beta, bl, br, wcat, g1, g0, bcat);
  hipLaunchKernelGGL(k_cast_wo, dim3(128), dim3(256), 0, stream, wo, wob);
  hipLaunchKernelGGL(k_norm, dim3(256), dim3(256), 0, stream, mask, invn);
  hipLaunchKernelGGL(k_proj, dim3(256), dim3(256), 0, stream,
                     act, mask, wcat, g1, g0, bcat, leftg, rightg);
  hipLaunchKernelGGL(k_main, dim3(1024), dim3(512), 0, stream,
                     leftg, rightg, wob, bo, invn, out);
}

// Round 3
// 160.113 us; speedup vs baseline: 1.0808x; 1.0808x over previous
//
#include <hip/hip_runtime.h>
#include <hip/hip_bf16.h>
#include <stdint.h>

#define R_ 256
#define S_ 128
#define C_ 256
#define CO_ 32
#define OUT_ 128
#define LN_EPS 1e-5f
#define EPS_ 1e-3f

typedef __attribute__((ext_vector_type(8))) short bf16x8;
typedef __attribute__((ext_vector_type(4))) float f32x4;
typedef __attribute__((address_space(1))) const unsigned int GAS;
typedef __attribute__((address_space(3))) unsigned int LAS;

static __device__ __forceinline__ unsigned short f2bf(float f) {
  union { float f; uint32_t u; } cv; cv.f = f;
  uint32_t u = cv.u;
  uint32_t r = (u + 0x7FFFu + ((u >> 16) & 1u)) >> 16;
  return (unsigned short)r;
}

// ============ merged prep: bid<64 weight-fold, 64..191 wo-permute+cast,
//              192..447 inv-norm table ============
__global__ __launch_bounds__(256) void k_prep(
    const float* wl, const float* wr, const float* gamma, const float* beta,
    const float* bl, const float* br, const float* wo, const float* mask,
    unsigned short* wcat, float* g1, float* g0, float* bcat,
    unsigned short* wob2, float* invn) {
  int bid = blockIdx.x, tid = threadIdx.x;
  if (bid < 64) {
    int co = bid, c = tid;
    const float* src = (co < 32) ? (wl + co * C_) : (wr + (co - 32) * C_);
    float w = src[c], g = gamma[c], bt = beta[c];
    float wg = w * g;
    wcat[co * C_ + c] = f2bf(wg);
    __shared__ float red1[256], red0[256];
    red1[c] = wg; red0[c] = w * bt;
    __syncthreads();
    for (int off = 128; off > 0; off >>= 1) {
      if (c < off) { red1[c] += red1[c + off]; red0[c] += red0[c + off]; }
      __syncthreads();
    }
    if (c == 0) {
      g1[co] = red1[0]; g0[co] = red0[0];
      bcat[co] = (co < 32) ? bl[co] : br[co - 32];
    }
  } else if (bid < 192) {
    // wob2[q][o][e] (u16): element = bf16(wo[o][kk]) at kk' = (kk&31)*32 + (kk>>5),
    // q = kk'>>3, e = kk'&7.  Layout: [128 q][128 o][8 e]
    int o = bid - 64;
    float4 v = ((const float4*)wo)[o * 256 + tid];
    float vv[4] = {v.x, v.y, v.z, v.w};
#pragma unroll
    for (int e = 0; e < 4; ++e) {
      int kk = tid * 4 + e;
      int kk2 = (kk & 31) * 32 + (kk >> 5);
      wob2[(kk2 >> 3) * 1024 + o * 8 + (kk2 & 7)] = f2bf(vv[e]);
    }
  } else {
    int i = bid - 192, j = tid;
    float a = 0.f;
    for (int s = 0; s < S_; ++s) a += mask[s * R_ + i] * mask[s * R_ + j];
    invn[i * R_ + j] = 1.0f / (EPS_ + a);
  }
}

// ============ projection: 512 blocks, (r, s-half) each; LN folded ============
#define AP2 264   // u16 per LDS row (256+8) -> 528B
__global__ __launch_bounds__(256, 2) void k_proj(
    const float* __restrict__ act, const float* __restrict__ mask,
    const unsigned short* __restrict__ wcat,
    const float* __restrict__ g1v, const float* __restrict__ g0v,
    const float* __restrict__ bcv,
    unsigned short* __restrict__ leftg, unsigned short* __restrict__ rightg) {
  __shared__ __align__(16) unsigned short a_bf[64 * AP2];   // 33792 B
  __shared__ __align__(16) unsigned short w_l[64 * AP2];    // 33792 B
  __shared__ __align__(16) unsigned short trans[64 * 72];   // 9216 B
  __shared__ float mu_s[64], rs_s[64], mk_s[64];
  __shared__ float g1s[64], g0s[64], bcs[64];
  int tid = threadIdx.x;
  int lane = tid & 63, w = tid >> 6;
  int r = blockIdx.x >> 1;
  int sh = (blockIdx.x & 1) * 64;

  // load 64 s-rows; each wave loads one full row per iter; stats via shfl
  const float4* actv = (const float4*)act;
  for (int it = 0; it < 16; ++it) {
    int s = w + it * 4;                       // local s 0..63
    float4 v = actv[(size_t)r * 8192 + (size_t)(sh + s) * 64 + lane];
    float ls = v.x + v.y + v.z + v.w;
    float lq = v.x * v.x + v.y * v.y + v.z * v.z + v.w * v.w;
#pragma unroll
    for (int off = 32; off > 0; off >>= 1) {
      ls += __shfl_xor(ls, off);
      lq += __shfl_xor(lq, off);
    }
    if (lane == 0) {
      float mu = ls * (1.0f / 256.0f);
      float var = lq * (1.0f / 256.0f) - mu * mu;
      mu_s[s] = mu;
      rs_s[s] = rsqrtf(var + LN_EPS);
    }
    ushort4 o;
    o.x = f2bf(v.x); o.y = f2bf(v.y); o.z = f2bf(v.z); o.w = f2bf(v.w);
    *(ushort4*)&a_bf[s * AP2 + lane * 4] = o;
  }
  const uint4* wsrc = (const uint4*)wcat;
  for (int it = 0; it < 8; ++it) {
    int f = tid + it * 256;                   // 0..2047
    int co = f >> 5, ch = f & 31;
    *(uint4*)&w_l[co * AP2 + ch * 8] = wsrc[f];
  }
  if (tid < 64) {
    mk_s[tid] = mask[(size_t)(sh + tid) * R_ + r];
    g1s[tid] = g1v[tid]; g0s[tid] = g0v[tid]; bcs[tid] = bcv[tid];
  }
  __syncthreads();

  // GEMM M=64(s) x N=64(co) x K=256; wave w owns s-rows w*16..+16
  int l15 = lane & 15, l4 = lane >> 4;
  f32x4 acc[4];
#pragma unroll
  for (int b = 0; b < 4; ++b) acc[b] = (f32x4){0.f, 0.f, 0.f, 0.f};
  for (int ks = 0; ks < 8; ++ks) {
    bf16x8 af = *(const bf16x8*)&a_bf[(w * 16 + l15) * AP2 + ks * 32 + l4 * 8];
#pragma unroll
    for (int nf = 0; nf < 4; ++nf) {
      bf16x8 bfr = *(const bf16x8*)&w_l[(nf * 16 + l15) * AP2 + ks * 32 + l4 * 8];
      acc[nf] = __builtin_amdgcn_mfma_f32_16x16x32_bf16(af, bfr, acc[nf], 0, 0, 0);
    }
  }
  // epilogue -> trans[co][s_local]
#pragma unroll
  for (int nf = 0; nf < 4; ++nf) {
    int co = nf * 16 + l15;
    float G1 = g1s[co], G0 = g0s[co], BC = bcs[co];
#pragma unroll
    for (int reg = 0; reg < 4; ++reg) {
      int s = w * 16 + l4 * 4 + reg;
      float v = rs_s[s] * acc[nf][reg] - mu_s[s] * rs_s[s] * G1 + G0 + BC;
      v *= mk_s[s];
      trans[co * 72 + s] = f2bf(v);
    }
  }
  __syncthreads();

  // write [r][co][sh..sh+64]
  for (int it2 = 0; it2 < 2; ++it2) {
    int idx = tid + it2 * 256;                // 0..511
    int row = idx >> 3, ch = idx & 7;
    uint4 val = *(const uint4*)&trans[row * 72 + ch * 8];
    if (row < 32)
      ((uint4*)leftg)[((size_t)(r * 32 + row)) * 16 + (sh >> 3) + ch] = val;
    else
      ((uint4*)rightg)[((size_t)(r * 32 + row - 32)) * 16 + (sh >> 3) + ch] = val;
  }
}

// ============ main kernel: 8x8 r-tile per block ============
// LDS: sa[256][128]u16 (64K) + sb (64K), linear 256B rows, source-swizzled.
// op buffer [64][1024]u16 aliases sa+sb after stage A.
__global__ __launch_bounds__(512, 2) void k_main(
    const unsigned short* __restrict__ leftg, const unsigned short* __restrict__ rightg,
    const unsigned short* __restrict__ wob2, const float* __restrict__ bo,
    const float* __restrict__ invn, float* __restrict__ out) {
  __shared__ __align__(16) unsigned char smem[131072];
  unsigned char* opbytes = smem;
  unsigned short* opu16 = (unsigned short*)smem;
  float* redf = (float*)smem;
  int tid = threadIdx.x;
  int lane = tid & 63, w = tid >> 6;
  int l15 = lane & 15, l4 = lane >> 4;
  int bi = blockIdx.x >> 5, bj = blockIdx.x & 31;

  // ---- stage slabs via global_load_lds, 16B, source-chunk-swizzled ----
  // LDS(row, q) holds global chunk (row, q ^ (row&7)); rows are 256B.
  {
    const unsigned char* gA = (const unsigned char*)leftg + (size_t)bi * 65536;
    const unsigned char* gB = (const unsigned char*)rightg + (size_t)bj * 65536;
#pragma unroll
    for (int k = 0; k < 8; ++k) {
      int rowbase = w * 32 + k * 4;           // wave-uniform
      int row = rowbase + (lane >> 4);
      int ch = (lane & 15) ^ (row & 7);
      __builtin_amdgcn_global_load_lds((GAS*)(gA + row * 256 + ch * 16),
                                       (LAS*)&smem[rowbase * 256], 16, 0, 0);
      __builtin_amdgcn_global_load_lds((GAS*)(gB + row * 256 + ch * 16),
                                       (LAS*)&smem[65536 + rowbase * 256], 16, 0, 0);
    }
  }
  __syncthreads();

  // ---- stage A: op[m=(i,c)][n=(j,d)] = sum_s L*R; M=N=256, K=128 ----
  int wm = w >> 2, wn = w & 3;                // 2 m-halves x 4 n-quarters
  f32x4 acc[8][4];
#pragma unroll
  for (int a = 0; a < 8; ++a)
#pragma unroll
    for (int b = 0; b < 4; ++b) acc[a][b] = (f32x4){0.f, 0.f, 0.f, 0.f};
  for (int ks = 0; ks < 4; ++ks) {
    bf16x8 af[8], bfr[4];
#pragma unroll
    for (int mf = 0; mf < 8; ++mf) {
      int row = wm * 128 + mf * 16 + l15;
      int ch = (ks * 4 + l4) ^ (row & 7);
      af[mf] = *(const bf16x8*)&smem[row * 256 + ch * 16];
    }
#pragma unroll
    for (int nf = 0; nf < 4; ++nf) {
      int row = wn * 64 + nf * 16 + l15;
      int ch = (ks * 4 + l4) ^ (row & 7);
      bfr[nf] = *(const bf16x8*)&smem[65536 + row * 256 + ch * 16];
    }
#pragma unroll
    for (int mf = 0; mf < 8; ++mf)
#pragma unroll
      for (int nf = 0; nf < 4; ++nf)
        acc[mf][nf] = __builtin_amdgcn_mfma_f32_16x16x32_bf16(af[mf], bfr[nf], acc[mf][nf], 0, 0, 0);
  }
  __syncthreads();   // slab reads done; op buffer aliases

  // ---- op write: [p=i*8+j][kk'=d*32+c] u16, 16B-chunk XOR-swizzled by (p&7),
  //      packed 8B stores (regs are consecutive c) ----
#pragma unroll
  for (int mf = 0; mf < 8; ++mf) {
#pragma unroll
    for (int nf = 0; nf < 4; ++nf) {
      int p = (wm * 4 + (mf >> 1)) * 8 + wn * 2 + (nf >> 1);
      int d = ((nf & 1) << 4) + l15;
      int c0 = ((mf & 1) << 4) + l4 * 4;
      int baddr = p * 2048 + ((d * 64 + c0 * 2) ^ ((p & 7) << 4));
      uint32_t h0 = f2bf(acc[mf][nf][0]), h1 = f2bf(acc[mf][nf][1]);
      uint32_t h2 = f2bf(acc[mf][nf][2]), h3 = f2bf(acc[mf][nf][3]);
      uint2 pk; pk.x = h0 | (h1 << 16); pk.y = h2 | (h3 << 16);
      *(uint2*)&opbytes[baddr] = pk;
    }
  }
  __syncthreads();

  // ---- stage B: out[p][o] = sum_kk' op[p][kk']*wo'[o][kk'] ----
  // 8 waves = 2 k-halves x 4 o-groups(32 cols). M=64, N=32/wave, K=512/wave.
  int kh = w >> 2, wn2 = w & 3;
  f32x4 acc2[4][2];
#pragma unroll
  for (int a = 0; a < 4; ++a) { acc2[a][0] = (f32x4){0,0,0,0}; acc2[a][1] = (f32x4){0,0,0,0}; }
  {
    const uint4* wv = (const uint4*)wob2;     // [128 q][128 o] uint4
    int ks0 = kh * 16;
#pragma unroll 2
    for (int ks2 = ks0; ks2 < ks0 + 16; ++ks2) {
      uint4 b0r = wv[(ks2 * 4 + l4) * 128 + wn2 * 32 + l15];
      uint4 b1r = wv[(ks2 * 4 + l4) * 128 + wn2 * 32 + 16 + l15];
      bf16x8 b0 = *(const bf16x8*)&b0r;
      bf16x8 b1 = *(const bf16x8*)&b1r;
      bf16x8 a2[4];
#pragma unroll
      for (int mf = 0; mf < 4; ++mf) {
        int p = mf * 16 + l15;
        int ch = (ks2 * 4 + l4) ^ (p & 7);
        a2[mf] = *(const bf16x8*)&opu16[p * 1024 + ch * 8];
      }
#pragma unroll
      for (int mf = 0; mf < 4; ++mf) {
        acc2[mf][0] = __builtin_amdgcn_mfma_f32_16x16x32_bf16(a2[mf], b0, acc2[mf][0], 0, 0, 0);
        acc2[mf][1] = __builtin_amdgcn_mfma_f32_16x16x32_bf16(a2[mf], b1, acc2[mf][1], 0, 0, 0);
      }
    }
  }
  __syncthreads();   // all op reads done; reduce buffer aliases

  // k-split reduce: waves 4..7 write partials (padded stride 144B), 0..3 add
  if (kh == 1) {
#pragma unroll
    for (int mf = 0; mf < 4; ++mf)
#pragma unroll
      for (int n2 = 0; n2 < 2; ++n2)
        *(f32x4*)&redf[((w - 4) * 64 + lane) * 36 + (mf * 2 + n2) * 4] = acc2[mf][n2];
  }
  __syncthreads();
  if (kh == 0) {
#pragma unroll
    for (int mf = 0; mf < 4; ++mf)
#pragma unroll
      for (int n2 = 0; n2 < 2; ++n2) {
        f32x4 pv = *(const f32x4*)&redf[(w * 64 + lane) * 36 + (mf * 2 + n2) * 4];
        acc2[mf][n2] += pv;
      }
    // epilogue
#pragma unroll
    for (int n2 = 0; n2 < 2; ++n2) {
      int o = wn2 * 32 + n2 * 16 + l15;
      float bov = bo[o];
#pragma unroll
      for (int mf = 0; mf < 4; ++mf) {
#pragma unroll
        for (int reg = 0; reg < 4; ++reg) {
          int p = mf * 16 + l4 * 4 + reg;
          int gi = bi * 8 + (p >> 3), gj = bj * 8 + (p & 7);
          float v = (acc2[mf][n2][reg] + bov) * invn[gi * R_ + gj];
          out[((size_t)(gi * R_ + gj)) * OUT_ + o] = v;
        }
      }
    }
  }
}

extern "C" void kernel_launch(void* const* d_in, const int* in_sizes, int n_in,
                              void* d_out, int out_size, void* d_ws, size_t ws_size,
                              hipStream_t stream) {
  (void)in_sizes; (void)n_in; (void)out_size; (void)ws_size;
  const float* act   = (const float*)d_in[0];
  const float* mask  = (const float*)d_in[1];
  const float* gamma = (const float*)d_in[2];
  const float* beta  = (const float*)d_in[3];
  const float* wl    = (const float*)d_in[4];
  const float* bl    = (const float*)d_in[5];
  const float* wr    = (const float*)d_in[6];
  const float* br    = (const float*)d_in[7];
  const float* wo    = (const float*)d_in[8];
  const float* bo    = (const float*)d_in[9];
  float* out = (float*)d_out;
  unsigned char* ws = (unsigned char*)d_ws;
  unsigned short* leftg  = (unsigned short*)(ws + 0);         // 2 MB
  unsigned short* rightg = (unsigned short*)(ws + 2097152);   // 2 MB
  unsigned short* wob2   = (unsigned short*)(ws + 4194304);   // 256 KB
  float* invn            = (float*)(ws + 4456448);            // 256 KB
  unsigned short* wcat   = (unsigned short*)(ws + 4718592);   // 32 KB
  float* g1              = (float*)(ws + 4751360);
  float* g0              = (float*)(ws + 4751616);
  float* bcat            = (float*)(ws + 4751872);

  hipLaunchKernelGGL(k_prep, dim3(448), dim3(256), 0, stream,
                     wl, wr, gamma, beta, bl, br, wo, mask,
                     wcat, g1, g0, bcat, wob2, invn);
  hipLaunchKernelGGL(k_proj, dim3(512), dim3(256), 0, stream,
                     act, mask, wcat, g1, g0, bcat, leftg, rightg);
  hipLaunchKernelGGL(k_main, dim3(1024), dim3(512), 0, stream,
                     leftg, rightg, wob2, bo, invn, out);
}

// Round 5
// 150.049 us; speedup vs baseline: 1.1533x; 1.0671x over previous
//
#include <hip/hip_runtime.h>
#include <hip/hip_bf16.h>
#include <stdint.h>

#define R_ 256
#define S_ 128
#define C_ 256
#define CO_ 32
#define OUT_ 128
#define LN_EPS 1e-5f
#define EPS_ 1e-3f

typedef __attribute__((ext_vector_type(8))) short bf16x8;
typedef __attribute__((ext_vector_type(4))) float f32x4;
typedef __attribute__((address_space(1))) const unsigned int GAS;
typedef __attribute__((address_space(3))) unsigned int LAS;

static __device__ __forceinline__ unsigned short f2bf(float f) {
  union { float f; uint32_t u; } cv; cv.f = f;
  uint32_t u = cv.u;
  uint32_t r = (u + 0x7FFFu + ((u >> 16) & 1u)) >> 16;
  return (unsigned short)r;
}

// ============ merged prep: bid<64 weight-fold, 64..191 wo-permute+cast,
//              192..447 inv-norm table ============
__global__ __launch_bounds__(256) void k_prep(
    const float* wl, const float* wr, const float* gamma, const float* beta,
    const float* bl, const float* br, const float* wo, const float* mask,
    unsigned short* wcat, float* g1, float* g0, float* bcat,
    unsigned short* wob2, float* invn) {
  int bid = blockIdx.x, tid = threadIdx.x;
  if (bid < 64) {
    int co = bid, c = tid;
    const float* src = (co < 32) ? (wl + co * C_) : (wr + (co - 32) * C_);
    float w = src[c], g = gamma[c], bt = beta[c];
    float wg = w * g;
    wcat[co * C_ + c] = f2bf(wg);
    __shared__ float red1[256], red0[256];
    red1[c] = wg; red0[c] = w * bt;
    __syncthreads();
    for (int off = 128; off > 0; off >>= 1) {
      if (c < off) { red1[c] += red1[c + off]; red0[c] += red0[c + off]; }
      __syncthreads();
    }
    if (c == 0) {
      g1[co] = red1[0]; g0[co] = red0[0];
      bcat[co] = (co < 32) ? bl[co] : br[co - 32];
    }
  } else if (bid < 192) {
    // wob2[q][o][e] (u16) = bf16(wo[o][kk]),  kk' = q*8+e = c*32+d  (c=kk&31, d=kk>>5)
    // => kk = ((q&3)*8+e)*32 + (q>>2).  One 16B store per (o, q).
    int o = bid - 64;
    if (tid < 128) {
      int q = tid;
      const float* row = wo + (size_t)o * 1024;
      int dd = q >> 2, cb = (q & 3) * 8;
      ushort4 lo, hi;
      lo.x = f2bf(row[(cb + 0) * 32 + dd]); lo.y = f2bf(row[(cb + 1) * 32 + dd]);
      lo.z = f2bf(row[(cb + 2) * 32 + dd]); lo.w = f2bf(row[(cb + 3) * 32 + dd]);
      hi.x = f2bf(row[(cb + 4) * 32 + dd]); hi.y = f2bf(row[(cb + 5) * 32 + dd]);
      hi.z = f2bf(row[(cb + 6) * 32 + dd]); hi.w = f2bf(row[(cb + 7) * 32 + dd]);
      *(ushort4*)&wob2[q * 1024 + o * 8] = lo;
      *(ushort4*)&wob2[q * 1024 + o * 8 + 4] = hi;
    }
  } else {
    int i = bid - 192, j = tid;
    float a = 0.f;
#pragma unroll 8
    for (int s = 0; s < S_; ++s) a += mask[s * R_ + i] * mask[s * R_ + j];
    invn[i * R_ + j] = 1.0f / (EPS_ + a);
  }
}

// ============ projection: 512 blocks, (r, s-half); LN folded; no shfl ============
#define AP2 264   // u16 per LDS row (256+8) -> 528B
__global__ __launch_bounds__(256, 2) void k_proj(
    const float* __restrict__ act, const float* __restrict__ mask,
    const unsigned short* __restrict__ wcat,
    const float* __restrict__ g1v, const float* __restrict__ g0v,
    const float* __restrict__ bcv,
    unsigned short* __restrict__ leftg, unsigned short* __restrict__ rightg) {
  __shared__ __align__(16) unsigned short a_bf[64 * AP2];   // 33792 B
  __shared__ __align__(16) unsigned short w_l[64 * AP2];    // 33792 B
  __shared__ __align__(16) unsigned short trans[64 * 72];   // 9216 B
  __shared__ float psum[64][4], psq[64][4];                 // 2048 B
  __shared__ float mu_s[64], rs_s[64], mk_s[64];
  __shared__ float g1s[64], g0s[64], bcs[64];
  int tid = threadIdx.x;
  int lane = tid & 63, w = tid >> 6;
  int r = blockIdx.x >> 1;
  int sh = (blockIdx.x & 1) * 64;

  // stage 64 s-rows, coalesced 1KB per wave-instr; no cross-lane ops
  const float4* actv = (const float4*)act;
  for (int it = 0; it < 16; ++it) {
    int s = w + it * 4;                       // local s 0..63
    float4 v = actv[(size_t)r * 8192 + (size_t)(sh + s) * 64 + lane];
    ushort4 o;
    o.x = f2bf(v.x); o.y = f2bf(v.y); o.z = f2bf(v.z); o.w = f2bf(v.w);
    *(ushort4*)&a_bf[s * AP2 + lane * 4] = o;
  }
  const uint4* wsrc = (const uint4*)wcat;
  for (int it = 0; it < 8; ++it) {
    int f = tid + it * 256;                   // 0..2047
    int co = f >> 5, ch = f & 31;
    *(uint4*)&w_l[co * AP2 + ch * 8] = wsrc[f];
  }
  if (tid < 64) {
    mk_s[tid] = mask[(size_t)(sh + tid) * R_ + r];
    g1s[tid] = g1v[tid]; g0s[tid] = g0v[tid]; bcs[tid] = bcv[tid];
  }
  __syncthreads();

  // stats: thread t -> row t>>2, interleaved c-chunks (t&3)*8 + k*32
  {
    int row = tid >> 2, cc = tid & 3;
    float sum = 0.f, sq = 0.f;
#pragma unroll
    for (int k = 0; k < 8; ++k) {
      uint4 v = *(const uint4*)&a_bf[row * AP2 + cc * 8 + k * 32];
      uint32_t ws_[4] = {v.x, v.y, v.z, v.w};
#pragma unroll
      for (int qd = 0; qd < 4; ++qd) {
        union { uint32_t u; float f; } lo, hi;
        lo.u = ws_[qd] << 16;
        hi.u = ws_[qd] & 0xFFFF0000u;
        sum += lo.f + hi.f;
        sq += lo.f * lo.f + hi.f * hi.f;
      }
    }
    psum[row][cc] = sum; psq[row][cc] = sq;
  }
  __syncthreads();
  if (tid < 64) {
    float s4 = psum[tid][0] + psum[tid][1] + psum[tid][2] + psum[tid][3];
    float q4 = psq[tid][0] + psq[tid][1] + psq[tid][2] + psq[tid][3];
    float mu = s4 * (1.0f / 256.0f);
    float var = q4 * (1.0f / 256.0f) - mu * mu;
    mu_s[tid] = mu;
    rs_s[tid] = rsqrtf(var + LN_EPS);
  }
  __syncthreads();

  // GEMM M=64(s) x N=64(co) x K=256; wave w owns s-rows w*16..+16
  int l15 = lane & 15, l4 = lane >> 4;
  f32x4 acc[4];
#pragma unroll
  for (int b = 0; b < 4; ++b) acc[b] = (f32x4){0.f, 0.f, 0.f, 0.f};
  for (int ks = 0; ks < 8; ++ks) {
    bf16x8 af = *(const bf16x8*)&a_bf[(w * 16 + l15) * AP2 + ks * 32 + l4 * 8];
#pragma unroll
    for (int nf = 0; nf < 4; ++nf) {
      bf16x8 bfr = *(const bf16x8*)&w_l[(nf * 16 + l15) * AP2 + ks * 32 + l4 * 8];
      acc[nf] = __builtin_amdgcn_mfma_f32_16x16x32_bf16(af, bfr, acc[nf], 0, 0, 0);
    }
  }
  // epilogue -> trans[co][s_local]
#pragma unroll
  for (int nf = 0; nf < 4; ++nf) {
    int co = nf * 16 + l15;
    float G1 = g1s[co], G0 = g0s[co], BC = bcs[co];
#pragma unroll
    for (int reg = 0; reg < 4; ++reg) {
      int s = w * 16 + l4 * 4 + reg;
      float v = rs_s[s] * acc[nf][reg] - mu_s[s] * rs_s[s] * G1 + G0 + BC;
      v *= mk_s[s];
      trans[co * 72 + s] = f2bf(v);
    }
  }
  __syncthreads();

  // write [r][co][sh..sh+64]
  for (int it2 = 0; it2 < 2; ++it2) {
    int idx = tid + it2 * 256;                // 0..511
    int row = idx >> 3, ch = idx & 7;
    uint4 val = *(const uint4*)&trans[row * 72 + ch * 8];
    if (row < 32)
      ((uint4*)leftg)[((size_t)(r * 32 + row)) * 16 + (sh >> 3) + ch] = val;
    else
      ((uint4*)rightg)[((size_t)(r * 32 + row - 32)) * 16 + (sh >> 3) + ch] = val;
  }
}

// ============ main kernel: 8x8 r-tile per block ============
// op chunk swizzle: sc(p,q) = q ^ (p&7) ^ ((q>>2)&7)   (q = kk'>>3, q>>2 = d)
__global__ __launch_bounds__(512, 1) void k_main(
    const unsigned short* __restrict__ leftg, const unsigned short* __restrict__ rightg,
    const unsigned short* __restrict__ wob2, const float* __restrict__ bo,
    const float* __restrict__ invn, float* __restrict__ out) {
  __shared__ __align__(16) unsigned char smem[131072];
  __shared__ float invt[64];
  __shared__ float bos[128];
  unsigned char* opbytes = smem;
  unsigned short* opu16 = (unsigned short*)smem;
  float* redf = (float*)smem;
  int tid = threadIdx.x;
  int lane = tid & 63, w = tid >> 6;
  int l15 = lane & 15, l4 = lane >> 4;
  int bi = blockIdx.x >> 5, bj = blockIdx.x & 31;

  if (tid < 64)
    invt[tid] = invn[(size_t)(bi * 8 + (tid >> 3)) * R_ + bj * 8 + (tid & 7)];
  else if (tid < 192)
    bos[tid - 64] = bo[tid - 64];

  // ---- stage slabs via global_load_lds, 16B, source-chunk-swizzled ----
  // LDS(row, k) holds global chunk (row, k ^ (row&7)); rows are 256B.
  {
    const unsigned char* gA = (const unsigned char*)leftg + (size_t)bi * 65536;
    const unsigned char* gB = (const unsigned char*)rightg + (size_t)bj * 65536;
#pragma unroll
    for (int k = 0; k < 8; ++k) {
      int rowbase = w * 32 + k * 4;           // wave-uniform
      int row = rowbase + (lane >> 4);
      int ch = (lane & 15) ^ (row & 7);
      __builtin_amdgcn_global_load_lds((GAS*)(gA + row * 256 + ch * 16),
                                       (LAS*)&smem[rowbase * 256], 16, 0, 0);
      __builtin_amdgcn_global_load_lds((GAS*)(gB + row * 256 + ch * 16),
                                       (LAS*)&smem[65536 + rowbase * 256], 16, 0, 0);
    }
  }
  __syncthreads();

  // ---- stage A: op[m=(i,c)][n=(j,d)] = sum_s L*R; M=N=256, K=128 ----
  int wm = w >> 2, wn = w & 3;                // 2 m-halves x 4 n-quarters
  f32x4 acc[8][4];
#pragma unroll
  for (int a = 0; a < 8; ++a)
#pragma unroll
    for (int b = 0; b < 4; ++b) acc[a][b] = (f32x4){0.f, 0.f, 0.f, 0.f};
  for (int ks = 0; ks < 4; ++ks) {
    bf16x8 af[8], bfr[4];
#pragma unroll
    for (int mf = 0; mf < 8; ++mf) {
      int row = wm * 128 + mf * 16 + l15;
      int ch = (ks * 4 + l4) ^ (row & 7);
      af[mf] = *(const bf16x8*)&smem[row * 256 + ch * 16];
    }
#pragma unroll
    for (int nf = 0; nf < 4; ++nf) {
      int row = wn * 64 + nf * 16 + l15;
      int ch = (ks * 4 + l4) ^ (row & 7);
      bfr[nf] = *(const bf16x8*)&smem[65536 + row * 256 + ch * 16];
    }
#pragma unroll
    for (int mf = 0; mf < 8; ++mf)
#pragma unroll
      for (int nf = 0; nf < 4; ++nf)
        acc[mf][nf] = __builtin_amdgcn_mfma_f32_16x16x32_bf16(af[mf], bfr[nf], acc[mf][nf], 0, 0, 0);
  }
  __syncthreads();   // slab reads done; op buffer aliases

  // ---- op write: row p (2048B), chunk sc(p,q), 8B half (l4&1) ----
#pragma unroll
  for (int mf = 0; mf < 8; ++mf) {
#pragma unroll
    for (int nf = 0; nf < 4; ++nf) {
      int p = (wm * 4 + (mf >> 1)) * 8 + wn * 2 + (nf >> 1);
      int d = ((nf & 1) << 4) + l15;
      int q = d * 4 + ((mf & 1) << 1) + (l4 >> 1);
      int sc = q ^ (p & 7) ^ (d & 7);
      int baddr = p * 2048 + sc * 16 + (l4 & 1) * 8;
      uint32_t h0 = f2bf(acc[mf][nf][0]), h1 = f2bf(acc[mf][nf][1]);
      uint32_t h2 = f2bf(acc[mf][nf][2]), h3 = f2bf(acc[mf][nf][3]);
      uint2 pk; pk.x = h0 | (h1 << 16); pk.y = h2 | (h3 << 16);
      *(uint2*)&opbytes[baddr] = pk;
    }
  }
  __syncthreads();

  // ---- stage B: out[p][o] = sum_kk' op[p][kk']*wo'[o][kk'] ----
  // 8 waves = 2 k-halves x 4 o-groups(32 cols). M=64, N=32/wave, K=512/wave.
  int kh = w >> 2, wn2 = w & 3;
  f32x4 acc2[4][2];
#pragma unroll
  for (int a = 0; a < 4; ++a) { acc2[a][0] = (f32x4){0,0,0,0}; acc2[a][1] = (f32x4){0,0,0,0}; }
  {
    const uint4* wv = (const uint4*)wob2;     // [128 q][128 o] uint4
    int ks0 = kh * 16;
    uint4 b0n = wv[(ks0 * 4 + l4) * 128 + wn2 * 32 + l15];
    uint4 b1n = wv[(ks0 * 4 + l4) * 128 + wn2 * 32 + 16 + l15];
#pragma unroll 4
    for (int ks2 = ks0; ks2 < ks0 + 16; ++ks2) {
      uint4 b0r = b0n, b1r = b1n;
      if (ks2 + 1 < ks0 + 16) {
        b0n = wv[((ks2 + 1) * 4 + l4) * 128 + wn2 * 32 + l15];
        b1n = wv[((ks2 + 1) * 4 + l4) * 128 + wn2 * 32 + 16 + l15];
      }
      bf16x8 b0 = *(const bf16x8*)&b0r;
      bf16x8 b1 = *(const bf16x8*)&b1r;
      bf16x8 a2[4];
#pragma unroll
      for (int mf = 0; mf < 4; ++mf) {
        int p = mf * 16 + l15;
        int q = ks2 * 4 + l4;
        int sc = q ^ (p & 7) ^ (ks2 & 7);
        a2[mf] = *(const bf16x8*)&opu16[p * 1024 + sc * 8];
      }
#pragma unroll
      for (int mf = 0; mf < 4; ++mf) {
        acc2[mf][0] = __builtin_amdgcn_mfma_f32_16x16x32_bf16(a2[mf], b0, acc2[mf][0], 0, 0, 0);
        acc2[mf][1] = __builtin_amdgcn_mfma_f32_16x16x32_bf16(a2[mf], b1, acc2[mf][1], 0, 0, 0);
      }
    }
  }
  __syncthreads();   // all op reads done; reduce buffer aliases

  // k-split reduce: waves 4..7 write partials (stride 36 dwords), 0..3 add
  if (kh == 1) {
#pragma unroll
    for (int mf = 0; mf < 4; ++mf)
#pragma unroll
      for (int n2 = 0; n2 < 2; ++n2)
        *(f32x4*)&redf[((w - 4) * 64 + lane) * 36 + (mf * 2 + n2) * 4] = acc2[mf][n2];
  }
  __syncthreads();
  if (kh == 0) {
#pragma unroll
    for (int mf = 0; mf < 4; ++mf)
#pragma unroll
      for (int n2 = 0; n2 < 2; ++n2) {
        f32x4 pv = *(const f32x4*)&redf[(w * 64 + lane) * 36 + (mf * 2 + n2) * 4];
        acc2[mf][n2] += pv;
      }
#pragma unroll
    for (int n2 = 0; n2 < 2; ++n2) {
      int o = wn2 * 32 + n2 * 16 + l15;
      float bov = bos[o];
#pragma unroll
      for (int mf = 0; mf < 4; ++mf) {
#pragma unroll
        for (int reg = 0; reg < 4; ++reg) {
          int p = mf * 16 + l4 * 4 + reg;
          int gi = bi * 8 + (p >> 3), gj = bj * 8 + (p & 7);
          float v = (acc2[mf][n2][reg] + bov) * invt[p];
          out[((size_t)(gi * R_ + gj)) * OUT_ + o] = v;
        }
      }
    }
  }
}

extern "C" void kernel_launch(void* const* d_in, const int* in_sizes, int n_in,
                              void* d_out, int out_size, void* d_ws, size_t ws_size,
                              hipStream_t stream) {
  (void)in_sizes; (void)n_in; (void)out_size; (void)ws_size;
  const float* act   = (const float*)d_in[0];
  const float* mask  = (const float*)d_in[1];
  const float* gamma = (const float*)d_in[2];
  const float* beta  = (const float*)d_in[3];
  const float* wl    = (const float*)d_in[4];
  const float* bl    = (const float*)d_in[5];
  const float* wr    = (const float*)d_in[6];
  const float* br    = (const float*)d_in[7];
  const float* wo    = (const float*)d_in[8];
  const float* bo    = (const float*)d_in[9];
  float* out = (float*)d_out;
  unsigned char* ws = (unsigned char*)d_ws;
  unsigned short* leftg  = (unsigned short*)(ws + 0);         // 2 MB
  unsigned short* rightg = (unsigned short*)(ws + 2097152);   // 2 MB
  unsigned short* wob2   = (unsigned short*)(ws + 4194304);   // 256 KB
  float* invn            = (float*)(ws + 4456448);            // 256 KB
  unsigned short* wcat   = (unsigned short*)(ws + 4718592);   // 32 KB
  float* g1              = (float*)(ws + 4751360);
  float* g0              = (float*)(ws + 4751616);
  float* bcat            = (float*)(ws + 4751872);

  hipLaunchKernelGGL(k_prep, dim3(448), dim3(256), 0, stream,
                     wl, wr, gamma, beta, bl, br, wo, mask,
                     wcat, g1, g0, bcat, wob2, invn);
  hipLaunchKernelGGL(k_proj, dim3(512), dim3(256), 0, stream,
                     act, mask, wcat, g1, g0, bcat, leftg, rightg);
  hipLaunchKernelGGL(k_main, dim3(1024), dim3(512), 0, stream,
                     leftg, rightg, wob2, bo, invn, out);
}